// Round 4
// baseline (1952.648 us; speedup 1.0000x reference)
//
#include <hip/hip_runtime.h>

typedef unsigned short u16;
typedef unsigned int u32;
typedef __bf16 bf16x8 __attribute__((ext_vector_type(8)));
typedef float f32x4 __attribute__((ext_vector_type(4)));

#define TT 1024

__device__ __forceinline__ u16 f2bf(float f) {
  u32 u = __float_as_uint(f);
  u32 r = (u + 0x7fffu + ((u >> 16) & 1u)) >> 16;
  return (u16)r;
}
__device__ __forceinline__ float bf2f(u16 b) {
  return __uint_as_float(((u32)b) << 16);
}

__device__ __forceinline__ void gl_lds16(const void* g, void* l) {
  __builtin_amdgcn_global_load_lds(
      (const __attribute__((address_space(1))) u32*)g,
      (__attribute__((address_space(3))) u32*)l, 16, 0, 0);
}

// ---------------- convert f32 -> bf16 ----------------
__global__ __launch_bounds__(256) void k_f32_to_bf16(const float* __restrict__ in,
                                                     u16* __restrict__ out, int n) {
  int i = (blockIdx.x * 256 + threadIdx.x) * 4;
  if (i >= n) return;
  float4 v = *(const float4*)(in + i);
  ushort4 o;
  o.x = f2bf(v.x); o.y = f2bf(v.y); o.z = f2bf(v.z); o.w = f2bf(v.w);
  *(ushort4*)(out + i) = o;
}

// ------- init residual: f32 copy + bf16 convert -------
__global__ __launch_bounds__(256) void k_init(const float* __restrict__ in,
                                              u16* __restrict__ bfo,
                                              float* __restrict__ fo, int n) {
  int i = (blockIdx.x * 256 + threadIdx.x) * 4;
  if (i >= n) return;
  float4 v = *(const float4*)(in + i);
  ushort4 o;
  o.x = f2bf(v.x); o.y = f2bf(v.y); o.z = f2bf(v.z); o.w = f2bf(v.w);
  *(ushort4*)(bfo + i) = o;
  *(float4*)(fo + i) = v;
}

// ------- transpose+convert: src f32 [R][C] -> dst bf16 [C][R] -------
struct TPack {
  const float* src[8];
  u16* dst[8];
};
__global__ __launch_bounds__(256) void k_transpose(TPack p, int R, int C) {
  __shared__ float tile[32][33];
  const int tx = threadIdx.x & 31;
  const int ty = threadIdx.x >> 5;
  const float* __restrict__ src = p.src[blockIdx.z];
  u16* __restrict__ dst = p.dst[blockIdx.z];
  const int c0 = blockIdx.x * 32;
  const int r0 = blockIdx.y * 32;
#pragma unroll
  for (int i = 0; i < 4; i++)
    tile[ty + i * 8][tx] = src[(size_t)(r0 + ty + i * 8) * C + c0 + tx];
  __syncthreads();
#pragma unroll
  for (int i = 0; i < 4; i++)
    dst[(size_t)(c0 + ty + i * 8) * R + r0 + tx] = f2bf(tile[tx][ty + i * 8]);
}

// ------- bf16 transpose: src [4096 rows][1024 cols within stride ld] -> dst [1024][4096] -------
__global__ __launch_bounds__(256) void k_tbf(const u16* __restrict__ src, int ld,
                                             u16* __restrict__ dst) {
  __shared__ u16 tile[32][33];
  const int r0 = blockIdx.y * 32;  // token tile
  const int c0 = blockIdx.x * 32;  // channel tile
  const int tr = threadIdx.x >> 3;        // 0..31
  const int tc = (threadIdx.x & 7) * 4;   // 0,4,..,28
  ushort4 v = *(const ushort4*)&src[(size_t)(r0 + tr) * ld + c0 + tc];
  tile[tr][tc] = v.x; tile[tr][tc + 1] = v.y; tile[tr][tc + 2] = v.z; tile[tr][tc + 3] = v.w;
  __syncthreads();
  ushort4 o;
  o.x = tile[tc][tr]; o.y = tile[tc + 1][tr]; o.z = tile[tc + 2][tr]; o.w = tile[tc + 3][tr];
  *(ushort4*)&dst[(size_t)(c0 + tr) * 4096 + r0 + tc] = o;
}

// ---------------- GEMM: C[M,N] = A[M,K] @ Bt[N,K]^T (bf16 in, f32 acc) ----------------
// Double-buffered LDS, single barrier per K-step (prefetch overlaps ds_read+MFMA).
// LDS chunk-swizzle: source chunk = (lane&3)^((srow>>1)&3), read chunk = quad^((lc>>1)&3)
// -> conflict-free ds_read_b128 (2-way = wave64 b128 floor).
// SPLITK>1: blockIdx.z selects a K-slice; z==0 writes Cout, z==1 writes Cout2 (f32 only).
template <int OUT_BF16, int RELU, int SPLITK>
__global__ __launch_bounds__(256) void k_gemm_tn(const u16* __restrict__ A,
                                                 const u16* __restrict__ Bt,
                                                 void* __restrict__ Cout,
                                                 void* __restrict__ Cout2,
                                                 int M, int N, int K) {
  __shared__ __attribute__((aligned(16))) u16 sA[2][128 * 32];
  __shared__ __attribute__((aligned(16))) u16 sB[2][128 * 32];
  const int tid = threadIdx.x;
  const int wave = tid >> 6;
  const int lane = tid & 63;
  const int quad = lane >> 4;
  const int lc = lane & 15;
  const int m0 = blockIdx.x * 128;
  const int n0 = blockIdx.y * 128;
  const int wr = (wave >> 1) * 64;
  const int wc = (wave & 1) * 64;

  const int Ks = K / SPLITK;
  const size_t kOff = (size_t)blockIdx.z * Ks;

  const int c0 = wave * 2, c1 = wave * 2 + 1;
  const int srow = lane >> 2;
  // inverse-swizzled source chunk (pairs with swizzled read below)
  const int scol = ((lane & 3) ^ ((srow >> 1) & 3)) * 8;

  const u16* a0 = A + (size_t)(m0 + c0 * 16 + srow) * K + kOff + scol;
  const u16* a1 = A + (size_t)(m0 + c1 * 16 + srow) * K + kOff + scol;
  const u16* b0 = Bt + (size_t)(n0 + c0 * 16 + srow) * K + kOff + scol;
  const u16* b1 = Bt + (size_t)(n0 + c1 * 16 + srow) * K + kOff + scol;

  f32x4 acc[4][4];
  const f32x4 z4 = {0.f, 0.f, 0.f, 0.f};
#pragma unroll
  for (int i = 0; i < 4; i++)
#pragma unroll
    for (int j = 0; j < 4; j++) acc[i][j] = z4;

  const int qs = quad ^ ((lc >> 1) & 3);  // swizzled read chunk

  auto stage = [&](int buf) {
    gl_lds16(a0, &sA[buf][c0 * 512]);
    gl_lds16(a1, &sA[buf][c1 * 512]);
    gl_lds16(b0, &sB[buf][c0 * 512]);
    gl_lds16(b1, &sB[buf][c1 * 512]);
    a0 += 32; a1 += 32; b0 += 32; b1 += 32;
  };

  stage(0);
  int cur = 0;
  for (int k0 = 0; k0 < Ks; k0 += 32) {
    __syncthreads();  // drains stage into buf[cur]; all waves done reading buf[cur^1]
    if (k0 + 32 < Ks) stage(cur ^ 1);  // prefetch flies under ds_read+MFMA below
    bf16x8 af[4], bfr[4];
#pragma unroll
    for (int i = 0; i < 4; i++)
      af[i] = *(const bf16x8*)&sA[cur][(wr + i * 16 + lc) * 32 + qs * 8];
#pragma unroll
    for (int j = 0; j < 4; j++)
      bfr[j] = *(const bf16x8*)&sB[cur][(wc + j * 16 + lc) * 32 + qs * 8];
#pragma unroll
    for (int i = 0; i < 4; i++)
#pragma unroll
      for (int j = 0; j < 4; j++)
        acc[i][j] = __builtin_amdgcn_mfma_f32_16x16x32_bf16(af[i], bfr[j], acc[i][j], 0, 0, 0);
    cur ^= 1;
  }

  void* Cw = (SPLITK > 1 && blockIdx.z == 1) ? Cout2 : Cout;
#pragma unroll
  for (int i = 0; i < 4; i++) {
    const int row = m0 + wr + i * 16 + quad * 4;
#pragma unroll
    for (int j = 0; j < 4; j++) {
      const int col = n0 + wc + j * 16 + lc;
#pragma unroll
      for (int r = 0; r < 4; r++) {
        float v = acc[i][j][r];
        if (RELU) v = fmaxf(v, 0.f);
        if (OUT_BF16)
          ((u16*)Cw)[(size_t)(row + r) * N + col] = f2bf(v);
        else
          ((float*)Cw)[(size_t)(row + r) * N + col] = v;
      }
    }
  }
}

// ---------------- flash attention (T=S=1024, H=16, D=64) ----------------
// QBLK=128 (8 waves), 1D grid 512 with XCD-aware remap: each XCD owns 8 heads
// (2 MB K/V -> fits per-XCD L2). K: [token][ch] stride ldk; Vt: [1024 ch][4096 tok].
// KVBLK=64, double-buffered LDS via global_load_lds with XOR-swizzled source,
// swizzled ds_read_b128 fragment reads; 1 barrier per tile; deferred l-sum.
template <int CAUSAL>
__global__ __launch_bounds__(512, 6) void k_flash(const u16* __restrict__ Q, int ldq,
                                                  const u16* __restrict__ K, int ldk,
                                                  const u16* __restrict__ Vt,
                                                  u16* __restrict__ O) {
  __shared__ __attribute__((aligned(16))) u16 sK[2][64 * 64];  // [key][dk], dk-blocks swizzled
  __shared__ __attribute__((aligned(16))) u16 sV[2][64 * 64];  // [dv][key], key-blocks swizzled
  __shared__ __attribute__((aligned(16))) u16 sP[8][16 * 64];  // per-wave, key-blocks swizzled
  const int tid = threadIdx.x;
  const int wave = tid >> 6;
  const int lane = tid & 63;
  const int quad = lane >> 4;
  const int lc = lane & 15;
  // XCD-aware remap: 512 blocks, xcd = id&7 owns heads y in [xcd*8, xcd*8+8)
  const int id = blockIdx.x;
  const int xcd = id & 7;
  const int s_ = id >> 3;          // 0..63
  const int y = xcd * 8 + (s_ >> 3);  // 0..63 (b,h pair)
  const int qb = s_ & 7;           // 0..7
  const int b = y >> 4;            // batch
  const int h = y & 15;            // head
  const size_t rowB = (size_t)b * TT;
  const int qrow = qb * 128 + wave * 16;
  const int hc = h * 64;

  const bf16x8 qf0 = *(const bf16x8*)&Q[(rowB + qrow + lc) * ldq + hc + quad * 8];
  const bf16x8 qf1 = *(const bf16x8*)&Q[(rowB + qrow + lc) * ldq + hc + 32 + quad * 8];

  f32x4 o[4];
  float m_r[4], l_r[4];
  const f32x4 z4 = {0.f, 0.f, 0.f, 0.f};
#pragma unroll
  for (int d = 0; d < 4; d++) o[d] = z4;
#pragma unroll
  for (int r = 0; r < 4; r++) { m_r[r] = -1e30f; l_r[r] = 0.f; }

  const float cvt = 1.4426950408889634f / 8.0f;  // log2(e)/sqrt(DK)
  u16* myP = sP[wave];
  const int l7 = lc & 7;
  const int swr = (lc >> 2) | ((lc & 1) << 2);  // P-read swizzle sw(row=lc)

  const int nkt = CAUSAL ? (2 * qb + 2) : 16;

  // staging: 512 threads cover 512 chunks of 16B per array (1 gl_lds each)
  const int prow = tid >> 3;                 // 0..63
  const int pcb = (tid & 7) ^ (prow & 7);    // inverse-swizzled source block
  const int p0 = wave * 64;                  // wave-uniform LDS base chunk

  auto stage = [&](int cur, int s0) {
    gl_lds16(K + (rowB + s0 + prow) * (size_t)ldk + hc + pcb * 8, &sK[cur][p0 * 8]);
    gl_lds16(Vt + (size_t)(hc + prow) * 4096 + rowB + s0 + pcb * 8, &sV[cur][p0 * 8]);
  };

  stage(0, 0);
  int cur = 0;
  for (int kt = 0; kt < nkt; kt++) {
    const int s0 = kt * 64;
    __syncthreads();  // drains vmcnt(0): buf[cur] ready; buf[cur^1] free for prefetch
    if (kt + 1 < nkt) stage(cur ^ 1, s0 + 64);

    // S = Q @ K^T : 4 sub-tiles of 16 keys
    f32x4 s[4];
#pragma unroll
    for (int st = 0; st < 4; st++) {
      const int key = st * 16 + lc;
      const bf16x8 kf0 = *(const bf16x8*)&sK[cur][key * 64 + ((quad ^ l7) * 8)];
      const bf16x8 kf1 = *(const bf16x8*)&sK[cur][key * 64 + (((4 + quad) ^ l7) * 8)];
      f32x4 z = z4;
      z = __builtin_amdgcn_mfma_f32_16x16x32_bf16(qf0, kf0, z, 0, 0, 0);
      z = __builtin_amdgcn_mfma_f32_16x16x32_bf16(qf1, kf1, z, 0, 0, 0);
      s[st] = z;
    }

    // online softmax (log2 domain); l kept as per-lane partial (reduced at end)
#pragma unroll
    for (int r = 0; r < 4; r++) {
      float sv0 = s[0][r] * cvt, sv1 = s[1][r] * cvt;
      float sv2 = s[2][r] * cvt, sv3 = s[3][r] * cvt;
      if (CAUSAL) {
        const int qg = qrow + quad * 4 + r;
        if (s0 + lc > qg) sv0 = -1e30f;
        if (s0 + 16 + lc > qg) sv1 = -1e30f;
        if (s0 + 32 + lc > qg) sv2 = -1e30f;
        if (s0 + 48 + lc > qg) sv3 = -1e30f;
      }
      float pm = fmaxf(fmaxf(sv0, sv1), fmaxf(sv2, sv3));
      pm = fmaxf(pm, __shfl_xor(pm, 1));
      pm = fmaxf(pm, __shfl_xor(pm, 2));
      pm = fmaxf(pm, __shfl_xor(pm, 4));
      pm = fmaxf(pm, __shfl_xor(pm, 8));
      const float mn = fmaxf(m_r[r], pm);
      const float al = exp2f(m_r[r] - mn);
      m_r[r] = mn;
      const float p0_ = exp2f(sv0 - mn);
      const float p1_ = exp2f(sv1 - mn);
      const float p2_ = exp2f(sv2 - mn);
      const float p3_ = exp2f(sv3 - mn);
      l_r[r] = l_r[r] * al + (p0_ + p1_ + p2_ + p3_);
      const int row = quad * 4 + r;
      const int sw = quad | ((r & 1) << 2);  // P-write swizzle sw(row)
      u16* pr = myP + row * 64 + l7;
      pr[(((lc >> 3) | 0) ^ sw) * 8] = f2bf(p0_);
      pr[(((lc >> 3) | 2) ^ sw) * 8] = f2bf(p1_);
      pr[(((lc >> 3) | 4) ^ sw) * 8] = f2bf(p2_);
      pr[(((lc >> 3) | 6) ^ sw) * 8] = f2bf(p3_);
#pragma unroll
      for (int d = 0; d < 4; d++) o[d][r] *= al;
    }

    // O += P @ V : two 32-key chunks (sP is per-wave private: no barrier needed)
#pragma unroll
    for (int c = 0; c < 2; c++) {
      const bf16x8 pf = *(const bf16x8*)&myP[lc * 64 + (((c * 4 + quad) ^ swr) * 8)];
#pragma unroll
      for (int d = 0; d < 4; d++) {
        const int dv = d * 16 + lc;
        const bf16x8 vf = *(const bf16x8*)&sV[cur][dv * 64 + (((c * 4 + quad) ^ l7) * 8)];
        o[d] = __builtin_amdgcn_mfma_f32_16x16x32_bf16(pf, vf, o[d], 0, 0, 0);
      }
    }
    cur ^= 1;
  }

#pragma unroll
  for (int r = 0; r < 4; r++) {
    float l = l_r[r];
    l += __shfl_xor(l, 1);
    l += __shfl_xor(l, 2);
    l += __shfl_xor(l, 4);
    l += __shfl_xor(l, 8);
    const float inv = 1.0f / l;
    const size_t orow = (rowB + qrow + quad * 4 + r) * 1024 + hc;
#pragma unroll
    for (int d = 0; d < 4; d++) O[orow + d * 16 + lc] = f2bf(o[d][r] * inv);
  }
}

// --------- residual + layernorm: xf = LN(y0 [+ y1] + xf) [f32]; xb = bf16(xf) ---------
template <int NSUM>
__global__ __launch_bounds__(256) void k_ln(const float* __restrict__ y0,
                                            const float* __restrict__ y1,
                                            float* __restrict__ xf,
                                            u16* __restrict__ xb,
                                            float* __restrict__ fout) {
  const int row = blockIdx.x;
  const int tid = threadIdx.x;
  const int lane = tid & 63, wave = tid >> 6;
  const size_t base = (size_t)row * 1024 + tid * 4;
  float4 v = *(const float4*)&y0[base];
  float4 xv = *(const float4*)&xf[base];
  if (NSUM == 2) {
    float4 w = *(const float4*)&y1[base];
    v.x += w.x; v.y += w.y; v.z += w.z; v.w += w.w;
  }
  v.x += xv.x; v.y += xv.y; v.z += xv.z; v.w += xv.w;
  float s = v.x + v.y + v.z + v.w;
  float ss = v.x * v.x + v.y * v.y + v.z * v.z + v.w * v.w;
#pragma unroll
  for (int off = 1; off < 64; off <<= 1) {
    s += __shfl_xor(s, off);
    ss += __shfl_xor(ss, off);
  }
  __shared__ float rs[4], rss[4];
  if (lane == 0) { rs[wave] = s; rss[wave] = ss; }
  __syncthreads();
  const float S = rs[0] + rs[1] + rs[2] + rs[3];
  const float SS = rss[0] + rss[1] + rss[2] + rss[3];
  const float mean = S * (1.f / 1024.f);
  const float var = SS * (1.f / 1024.f) - mean * mean;
  const float inv = rsqrtf(var + 1e-5f);
  const float o0 = (v.x - mean) * inv, o1 = (v.y - mean) * inv;
  const float o2 = (v.z - mean) * inv, o3 = (v.w - mean) * inv;
  float4 fo; fo.x = o0; fo.y = o1; fo.z = o2; fo.w = o3;
  *(float4*)&xf[base] = fo;
  ushort4 ob;
  ob.x = f2bf(o0); ob.y = f2bf(o1); ob.z = f2bf(o2); ob.w = f2bf(o3);
  *(ushort4*)&xb[base] = ob;
  if (fout) *(float4*)&fout[base] = fo;
}

extern "C" void kernel_launch(void* const* d_in, const int* in_sizes, int n_in,
                              void* d_out, int out_size, void* d_ws, size_t ws_size,
                              hipStream_t stream) {
  const float* dec_inputs  = (const float*)d_in[0];
  const float* enc_outputs = (const float*)d_in[1];
  const float* self_Wq = (const float*)d_in[4];
  const float* self_Wk = (const float*)d_in[5];
  const float* self_Wv = (const float*)d_in[6];
  const float* self_Wo = (const float*)d_in[7];
  const float* cross_Wq = (const float*)d_in[8];
  const float* cross_Wk = (const float*)d_in[9];
  const float* cross_Wv = (const float*)d_in[10];
  const float* cross_Wo = (const float*)d_in[11];
  const float* ffn_W1 = (const float*)d_in[12];
  const float* ffn_W2 = (const float*)d_in[13];

  char* ws = (char*)d_ws;
  const size_t MB = 1024 * 1024;
  // bf16 weight staging (per layer, transposed to [N,K])
  u16* wq_t = (u16*)(ws + 0 * MB);   // [3072,1024] contiguous: wq,wk,wv
  u16* wk_t = (u16*)(ws + 2 * MB);
  u16* wv_t = (u16*)(ws + 4 * MB);
  u16* wo_t = (u16*)(ws + 6 * MB);
  u16* cq_t = (u16*)(ws + 8 * MB);
  u16* ck_t = (u16*)(ws + 10 * MB);  // [2048,1024] contiguous: ck,cv
  u16* cv_t = (u16*)(ws + 12 * MB);
  u16* co_t = (u16*)(ws + 14 * MB);
  u16* w1_t = (u16*)(ws + 16 * MB);  // [4096,1024]
  u16* w2_t = (u16*)(ws + 24 * MB);  // [1024,4096]
  u16* encb = (u16*)(ws + 32 * MB);  // [4096,1024] bf16
  u16* xb   = (u16*)(ws + 40 * MB);  // [4096,1024] bf16 copy of residual
  u16* qkv  = (u16*)(ws + 48 * MB);  // [4096,3072] self / cross q
  u16* kvb  = (u16*)(ws + 56 * MB);  // [4096,2048] cross K,V
  u16* ctx  = (u16*)(ws + 72 * MB);  // [4096,1024]
  u16* hbuf = (u16*)(ws + 48 * MB);  // [4096,4096] (overlays qkv+kvb+ctx in FFN)
  float* yb = (float*)(ws + 80 * MB);  // [4096,1024] f32 GEMM out
  u16* vtb  = (u16*)(ws + 80 * MB);    // [1024 ch][4096 tok] V^T (overlays yb; disjoint in time)
  float* xf = (float*)(ws + 96 * MB);  // [4096,1024] f32 residual stream
  // split-K second buffers (16 MB f32 each), placed over regions dead at their call site:
  float* ysA = (float*)(ws + 48 * MB); // over qkv/kvb: dead after flash (wo/co GEMMs)
  float* ysW = (float*)(ws + 0 * MB);  // over self/cross W_t: dead during FFN W2

  const int NTOK = 4 * TT * 1024;  // 4M elements

  k_init<<<4096, 256, 0, stream>>>(dec_inputs, xb, xf, NTOK);
  k_f32_to_bf16<<<4096, 256, 0, stream>>>(enc_outputs, encb, NTOK);

  for (int l = 0; l < 4; l++) {
    const size_t sqOff = (size_t)l * 1024 * 1024;
    const size_t ffOff = (size_t)l * 4096 * 1024;
    TPack sq;
    sq.src[0] = self_Wq + sqOff;  sq.dst[0] = wq_t;
    sq.src[1] = self_Wk + sqOff;  sq.dst[1] = wk_t;
    sq.src[2] = self_Wv + sqOff;  sq.dst[2] = wv_t;
    sq.src[3] = self_Wo + sqOff;  sq.dst[3] = wo_t;
    sq.src[4] = cross_Wq + sqOff; sq.dst[4] = cq_t;
    sq.src[5] = cross_Wk + sqOff; sq.dst[5] = ck_t;
    sq.src[6] = cross_Wv + sqOff; sq.dst[6] = cv_t;
    sq.src[7] = cross_Wo + sqOff; sq.dst[7] = co_t;
    k_transpose<<<dim3(32, 32, 8), 256, 0, stream>>>(sq, 1024, 1024);
    TPack p1 = sq; p1.src[0] = ffn_W1 + ffOff; p1.dst[0] = w1_t;
    k_transpose<<<dim3(128, 32, 1), 256, 0, stream>>>(p1, 1024, 4096);
    TPack p2 = sq; p2.src[0] = ffn_W2 + ffOff; p2.dst[0] = w2_t;
    k_transpose<<<dim3(32, 128, 1), 256, 0, stream>>>(p2, 4096, 1024);

    // ---- self attention ----
    k_gemm_tn<1, 0, 1><<<dim3(32, 24), 256, 0, stream>>>(xb, wq_t, qkv, nullptr, 4096, 3072, 1024);
    k_tbf<<<dim3(32, 128), 256, 0, stream>>>(qkv + 2048, 3072, vtb);
    k_flash<1><<<512, 512, 0, stream>>>(qkv, 3072, qkv + 1024, 3072, vtb, ctx);
    k_gemm_tn<0, 0, 2><<<dim3(32, 8, 2), 256, 0, stream>>>(ctx, wo_t, yb, ysA, 4096, 1024, 1024);
    k_ln<2><<<4096, 256, 0, stream>>>(yb, ysA, xf, xb, nullptr);

    // ---- cross attention ----
    k_gemm_tn<1, 0, 1><<<dim3(32, 8), 256, 0, stream>>>(xb, cq_t, qkv, nullptr, 4096, 1024, 1024);
    k_gemm_tn<1, 0, 1><<<dim3(32, 16), 256, 0, stream>>>(encb, ck_t, kvb, nullptr, 4096, 2048, 1024);
    k_tbf<<<dim3(32, 128), 256, 0, stream>>>(kvb + 1024, 2048, vtb);
    k_flash<0><<<512, 512, 0, stream>>>(qkv, 1024, kvb, 2048, vtb, ctx);
    k_gemm_tn<0, 0, 2><<<dim3(32, 8, 2), 256, 0, stream>>>(ctx, co_t, yb, ysA, 4096, 1024, 1024);
    k_ln<2><<<4096, 256, 0, stream>>>(yb, ysA, xf, xb, nullptr);

    // ---- FFN ----
    k_gemm_tn<1, 1, 1><<<dim3(32, 32), 256, 0, stream>>>(xb, w1_t, hbuf, nullptr, 4096, 4096, 1024);
    k_gemm_tn<0, 0, 2><<<dim3(32, 8, 2), 256, 0, stream>>>(hbuf, w2_t, yb, ysW, 4096, 1024, 4096);
    k_ln<2><<<4096, 256, 0, stream>>>(yb, ysW, xf, xb, (l == 3) ? (float*)d_out : nullptr);
  }
}

// Round 5
// 1806.002 us; speedup vs baseline: 1.0812x; 1.0812x over previous
//
#include <hip/hip_runtime.h>

typedef unsigned short u16;
typedef unsigned int u32;
typedef __bf16 bf16x8 __attribute__((ext_vector_type(8)));
typedef float f32x4 __attribute__((ext_vector_type(4)));

#define TT 1024

__device__ __forceinline__ u16 f2bf(float f) {
  u32 u = __float_as_uint(f);
  u32 r = (u + 0x7fffu + ((u >> 16) & 1u)) >> 16;
  return (u16)r;
}
__device__ __forceinline__ float bf2f(u16 b) {
  return __uint_as_float(((u32)b) << 16);
}

__device__ __forceinline__ void gl_lds16(const void* g, void* l) {
  __builtin_amdgcn_global_load_lds(
      (const __attribute__((address_space(1))) u32*)g,
      (__attribute__((address_space(3))) u32*)l, 16, 0, 0);
}

// ---------------- convert f32 -> bf16 ----------------
__global__ __launch_bounds__(256) void k_f32_to_bf16(const float* __restrict__ in,
                                                     u16* __restrict__ out, int n) {
  int i = (blockIdx.x * 256 + threadIdx.x) * 4;
  if (i >= n) return;
  float4 v = *(const float4*)(in + i);
  ushort4 o;
  o.x = f2bf(v.x); o.y = f2bf(v.y); o.z = f2bf(v.z); o.w = f2bf(v.w);
  *(ushort4*)(out + i) = o;
}

// ------- init residual: f32 copy + bf16 convert -------
__global__ __launch_bounds__(256) void k_init(const float* __restrict__ in,
                                              u16* __restrict__ bfo,
                                              float* __restrict__ fo, int n) {
  int i = (blockIdx.x * 256 + threadIdx.x) * 4;
  if (i >= n) return;
  float4 v = *(const float4*)(in + i);
  ushort4 o;
  o.x = f2bf(v.x); o.y = f2bf(v.y); o.z = f2bf(v.z); o.w = f2bf(v.w);
  *(ushort4*)(bfo + i) = o;
  *(float4*)(fo + i) = v;
}

// ------- transpose+convert: src f32 [R][C] -> dst bf16 [C][R] -------
struct TPack {
  const float* src[8];
  u16* dst[8];
};
__global__ __launch_bounds__(256) void k_transpose(TPack p, int R, int C) {
  __shared__ float tile[32][33];
  const int tx = threadIdx.x & 31;
  const int ty = threadIdx.x >> 5;
  const float* __restrict__ src = p.src[blockIdx.z];
  u16* __restrict__ dst = p.dst[blockIdx.z];
  const int c0 = blockIdx.x * 32;
  const int r0 = blockIdx.y * 32;
#pragma unroll
  for (int i = 0; i < 4; i++)
    tile[ty + i * 8][tx] = src[(size_t)(r0 + ty + i * 8) * C + c0 + tx];
  __syncthreads();
#pragma unroll
  for (int i = 0; i < 4; i++)
    dst[(size_t)(c0 + ty + i * 8) * R + r0 + tx] = f2bf(tile[tx][ty + i * 8]);
}

// ------- bf16 transpose: src [4096 rows][1024 cols within stride ld] -> dst [1024][4096] -------
__global__ __launch_bounds__(256) void k_tbf(const u16* __restrict__ src, int ld,
                                             u16* __restrict__ dst) {
  __shared__ u16 tile[32][33];
  const int r0 = blockIdx.y * 32;  // token tile
  const int c0 = blockIdx.x * 32;  // channel tile
  const int tr = threadIdx.x >> 3;        // 0..31
  const int tc = (threadIdx.x & 7) * 4;   // 0,4,..,28
  ushort4 v = *(const ushort4*)&src[(size_t)(r0 + tr) * ld + c0 + tc];
  tile[tr][tc] = v.x; tile[tr][tc + 1] = v.y; tile[tr][tc + 2] = v.z; tile[tr][tc + 3] = v.w;
  __syncthreads();
  ushort4 o;
  o.x = tile[tc][tr]; o.y = tile[tc + 1][tr]; o.z = tile[tc + 2][tr]; o.w = tile[tc + 3][tr];
  *(ushort4*)&dst[(size_t)(c0 + tr) * 4096 + r0 + tc] = o;
}

// ---------------- GEMM: C[M,N] = A[M,K] @ Bt[N,K]^T (bf16 in, f32 acc) ----------------
// Double-buffered LDS, single barrier per K-step (prefetch overlaps ds_read+MFMA).
// LDS chunk-swizzle: source chunk = (lane&3)^((srow>>1)&3), read chunk = quad^((lc>>1)&3)
// -> conflict-free ds_read_b128 (2-way = wave64 b128 floor).
// SPLITK>1: blockIdx.z selects a K-slice; z==0 writes Cout, z==1 writes Cout2 (f32 only).
template <int OUT_BF16, int RELU, int SPLITK>
__global__ __launch_bounds__(256) void k_gemm_tn(const u16* __restrict__ A,
                                                 const u16* __restrict__ Bt,
                                                 void* __restrict__ Cout,
                                                 void* __restrict__ Cout2,
                                                 int M, int N, int K) {
  __shared__ __attribute__((aligned(16))) u16 sA[2][128 * 32];
  __shared__ __attribute__((aligned(16))) u16 sB[2][128 * 32];
  const int tid = threadIdx.x;
  const int wave = tid >> 6;
  const int lane = tid & 63;
  const int quad = lane >> 4;
  const int lc = lane & 15;
  const int m0 = blockIdx.x * 128;
  const int n0 = blockIdx.y * 128;
  const int wr = (wave >> 1) * 64;
  const int wc = (wave & 1) * 64;

  const int Ks = K / SPLITK;
  const size_t kOff = (size_t)blockIdx.z * Ks;

  const int c0 = wave * 2, c1 = wave * 2 + 1;
  const int srow = lane >> 2;
  // inverse-swizzled source chunk (pairs with swizzled read below)
  const int scol = ((lane & 3) ^ ((srow >> 1) & 3)) * 8;

  const u16* a0 = A + (size_t)(m0 + c0 * 16 + srow) * K + kOff + scol;
  const u16* a1 = A + (size_t)(m0 + c1 * 16 + srow) * K + kOff + scol;
  const u16* b0 = Bt + (size_t)(n0 + c0 * 16 + srow) * K + kOff + scol;
  const u16* b1 = Bt + (size_t)(n0 + c1 * 16 + srow) * K + kOff + scol;

  f32x4 acc[4][4];
  const f32x4 z4 = {0.f, 0.f, 0.f, 0.f};
#pragma unroll
  for (int i = 0; i < 4; i++)
#pragma unroll
    for (int j = 0; j < 4; j++) acc[i][j] = z4;

  const int qs = quad ^ ((lc >> 1) & 3);  // swizzled read chunk

  auto stage = [&](int buf) {
    gl_lds16(a0, &sA[buf][c0 * 512]);
    gl_lds16(a1, &sA[buf][c1 * 512]);
    gl_lds16(b0, &sB[buf][c0 * 512]);
    gl_lds16(b1, &sB[buf][c1 * 512]);
    a0 += 32; a1 += 32; b0 += 32; b1 += 32;
  };

  stage(0);
  int cur = 0;
  for (int k0 = 0; k0 < Ks; k0 += 32) {
    __syncthreads();  // drains stage into buf[cur]; all waves done reading buf[cur^1]
    if (k0 + 32 < Ks) stage(cur ^ 1);  // prefetch flies under ds_read+MFMA below
    bf16x8 af[4], bfr[4];
#pragma unroll
    for (int i = 0; i < 4; i++)
      af[i] = *(const bf16x8*)&sA[cur][(wr + i * 16 + lc) * 32 + qs * 8];
#pragma unroll
    for (int j = 0; j < 4; j++)
      bfr[j] = *(const bf16x8*)&sB[cur][(wc + j * 16 + lc) * 32 + qs * 8];
#pragma unroll
    for (int i = 0; i < 4; i++)
#pragma unroll
      for (int j = 0; j < 4; j++)
        acc[i][j] = __builtin_amdgcn_mfma_f32_16x16x32_bf16(af[i], bfr[j], acc[i][j], 0, 0, 0);
    cur ^= 1;
  }

  void* Cw = (SPLITK > 1 && blockIdx.z == 1) ? Cout2 : Cout;
#pragma unroll
  for (int i = 0; i < 4; i++) {
    const int row = m0 + wr + i * 16 + quad * 4;
#pragma unroll
    for (int j = 0; j < 4; j++) {
      const int col = n0 + wc + j * 16 + lc;
#pragma unroll
      for (int r = 0; r < 4; r++) {
        float v = acc[i][j][r];
        if (RELU) v = fmaxf(v, 0.f);
        if (OUT_BF16)
          ((u16*)Cw)[(size_t)(row + r) * N + col] = f2bf(v);
        else
          ((float*)Cw)[(size_t)(row + r) * N + col] = v;
      }
    }
  }
}

// ---------------- flash attention (T=S=1024, H=16, D=64) ----------------
// QBLK=128 (8 waves), 1D grid 512 with XCD-aware remap: each XCD owns 8 heads
// (2 MB K/V -> fits per-XCD L2). K: [token][ch] stride ldk; Vt: [1024 ch][4096 tok].
// KVBLK=64, double-buffered LDS via global_load_lds with XOR-swizzled source,
// swizzled ds_read_b128 fragment reads; 1 barrier per tile; deferred l-sum.
// NOTE: min-waves hint = 4 (NOT 6): 6 capped VGPR at 40 -> accumulator spills,
// WRITE_SIZE 8MB->85MB scratch traffic (round-4 regression). LDS already limits
// to 3 blocks/CU; VGPR cap 128 keeps all state resident.
template <int CAUSAL>
__global__ __launch_bounds__(512, 4) void k_flash(const u16* __restrict__ Q, int ldq,
                                                  const u16* __restrict__ K, int ldk,
                                                  const u16* __restrict__ Vt,
                                                  u16* __restrict__ O) {
  __shared__ __attribute__((aligned(16))) u16 sK[2][64 * 64];  // [key][dk], dk-blocks swizzled
  __shared__ __attribute__((aligned(16))) u16 sV[2][64 * 64];  // [dv][key], key-blocks swizzled
  __shared__ __attribute__((aligned(16))) u16 sP[8][16 * 64];  // per-wave, key-blocks swizzled
  const int tid = threadIdx.x;
  const int wave = tid >> 6;
  const int lane = tid & 63;
  const int quad = lane >> 4;
  const int lc = lane & 15;
  // XCD-aware remap: 512 blocks, xcd = id&7 owns heads y in [xcd*8, xcd*8+8)
  const int id = blockIdx.x;
  const int xcd = id & 7;
  const int s_ = id >> 3;          // 0..63
  const int y = xcd * 8 + (s_ >> 3);  // 0..63 (b,h pair)
  const int qb = s_ & 7;           // 0..7
  const int b = y >> 4;            // batch
  const int h = y & 15;            // head
  const size_t rowB = (size_t)b * TT;
  const int qrow = qb * 128 + wave * 16;
  const int hc = h * 64;

  const bf16x8 qf0 = *(const bf16x8*)&Q[(rowB + qrow + lc) * ldq + hc + quad * 8];
  const bf16x8 qf1 = *(const bf16x8*)&Q[(rowB + qrow + lc) * ldq + hc + 32 + quad * 8];

  f32x4 o[4];
  float m_r[4], l_r[4];
  const f32x4 z4 = {0.f, 0.f, 0.f, 0.f};
#pragma unroll
  for (int d = 0; d < 4; d++) o[d] = z4;
#pragma unroll
  for (int r = 0; r < 4; r++) { m_r[r] = -1e30f; l_r[r] = 0.f; }

  const float cvt = 1.4426950408889634f / 8.0f;  // log2(e)/sqrt(DK)
  u16* myP = sP[wave];
  const int l7 = lc & 7;
  const int swr = (lc >> 2) | ((lc & 1) << 2);  // P-read swizzle sw(row=lc)

  const int nkt = CAUSAL ? (2 * qb + 2) : 16;

  // staging: 512 threads cover 512 chunks of 16B per array (1 gl_lds each)
  const int prow = tid >> 3;                 // 0..63
  const int pcb = (tid & 7) ^ (prow & 7);    // inverse-swizzled source block
  const int p0 = wave * 64;                  // wave-uniform LDS base chunk

  auto stage = [&](int cur, int s0) {
    gl_lds16(K + (rowB + s0 + prow) * (size_t)ldk + hc + pcb * 8, &sK[cur][p0 * 8]);
    gl_lds16(Vt + (size_t)(hc + prow) * 4096 + rowB + s0 + pcb * 8, &sV[cur][p0 * 8]);
  };

  stage(0, 0);
  int cur = 0;
  for (int kt = 0; kt < nkt; kt++) {
    const int s0 = kt * 64;
    __syncthreads();  // drains vmcnt(0): buf[cur] ready; buf[cur^1] free for prefetch
    if (kt + 1 < nkt) stage(cur ^ 1, s0 + 64);

    // S = Q @ K^T : 4 sub-tiles of 16 keys
    f32x4 s[4];
#pragma unroll
    for (int st = 0; st < 4; st++) {
      const int key = st * 16 + lc;
      const bf16x8 kf0 = *(const bf16x8*)&sK[cur][key * 64 + ((quad ^ l7) * 8)];
      const bf16x8 kf1 = *(const bf16x8*)&sK[cur][key * 64 + (((4 + quad) ^ l7) * 8)];
      f32x4 z = z4;
      z = __builtin_amdgcn_mfma_f32_16x16x32_bf16(qf0, kf0, z, 0, 0, 0);
      z = __builtin_amdgcn_mfma_f32_16x16x32_bf16(qf1, kf1, z, 0, 0, 0);
      s[st] = z;
    }

    // online softmax (log2 domain); l kept as per-lane partial (reduced at end)
#pragma unroll
    for (int r = 0; r < 4; r++) {
      float sv0 = s[0][r] * cvt, sv1 = s[1][r] * cvt;
      float sv2 = s[2][r] * cvt, sv3 = s[3][r] * cvt;
      if (CAUSAL) {
        const int qg = qrow + quad * 4 + r;
        if (s0 + lc > qg) sv0 = -1e30f;
        if (s0 + 16 + lc > qg) sv1 = -1e30f;
        if (s0 + 32 + lc > qg) sv2 = -1e30f;
        if (s0 + 48 + lc > qg) sv3 = -1e30f;
      }
      float pm = fmaxf(fmaxf(sv0, sv1), fmaxf(sv2, sv3));
      pm = fmaxf(pm, __shfl_xor(pm, 1));
      pm = fmaxf(pm, __shfl_xor(pm, 2));
      pm = fmaxf(pm, __shfl_xor(pm, 4));
      pm = fmaxf(pm, __shfl_xor(pm, 8));
      const float mn = fmaxf(m_r[r], pm);
      const float al = exp2f(m_r[r] - mn);
      m_r[r] = mn;
      const float p0_ = exp2f(sv0 - mn);
      const float p1_ = exp2f(sv1 - mn);
      const float p2_ = exp2f(sv2 - mn);
      const float p3_ = exp2f(sv3 - mn);
      l_r[r] = l_r[r] * al + (p0_ + p1_ + p2_ + p3_);
      const int row = quad * 4 + r;
      const int sw = quad | ((r & 1) << 2);  // P-write swizzle sw(row)
      u16* pr = myP + row * 64 + l7;
      pr[(((lc >> 3) | 0) ^ sw) * 8] = f2bf(p0_);
      pr[(((lc >> 3) | 2) ^ sw) * 8] = f2bf(p1_);
      pr[(((lc >> 3) | 4) ^ sw) * 8] = f2bf(p2_);
      pr[(((lc >> 3) | 6) ^ sw) * 8] = f2bf(p3_);
#pragma unroll
      for (int d = 0; d < 4; d++) o[d][r] *= al;
    }

    // O += P @ V : two 32-key chunks (sP is per-wave private: no barrier needed)
#pragma unroll
    for (int c = 0; c < 2; c++) {
      const bf16x8 pf = *(const bf16x8*)&myP[lc * 64 + (((c * 4 + quad) ^ swr) * 8)];
#pragma unroll
      for (int d = 0; d < 4; d++) {
        const int dv = d * 16 + lc;
        const bf16x8 vf = *(const bf16x8*)&sV[cur][dv * 64 + (((c * 4 + quad) ^ l7) * 8)];
        o[d] = __builtin_amdgcn_mfma_f32_16x16x32_bf16(pf, vf, o[d], 0, 0, 0);
      }
    }
    cur ^= 1;
  }

#pragma unroll
  for (int r = 0; r < 4; r++) {
    float l = l_r[r];
    l += __shfl_xor(l, 1);
    l += __shfl_xor(l, 2);
    l += __shfl_xor(l, 4);
    l += __shfl_xor(l, 8);
    const float inv = 1.0f / l;
    const size_t orow = (rowB + qrow + quad * 4 + r) * 1024 + hc;
#pragma unroll
    for (int d = 0; d < 4; d++) O[orow + d * 16 + lc] = f2bf(o[d][r] * inv);
  }
}

// --------- residual + layernorm: xf = LN(y0 [+ y1] + xf) [f32]; xb = bf16(xf) ---------
template <int NSUM>
__global__ __launch_bounds__(256) void k_ln(const float* __restrict__ y0,
                                            const float* __restrict__ y1,
                                            float* __restrict__ xf,
                                            u16* __restrict__ xb,
                                            float* __restrict__ fout) {
  const int row = blockIdx.x;
  const int tid = threadIdx.x;
  const int lane = tid & 63, wave = tid >> 6;
  const size_t base = (size_t)row * 1024 + tid * 4;
  float4 v = *(const float4*)&y0[base];
  float4 xv = *(const float4*)&xf[base];
  if (NSUM == 2) {
    float4 w = *(const float4*)&y1[base];
    v.x += w.x; v.y += w.y; v.z += w.z; v.w += w.w;
  }
  v.x += xv.x; v.y += xv.y; v.z += xv.z; v.w += xv.w;
  float s = v.x + v.y + v.z + v.w;
  float ss = v.x * v.x + v.y * v.y + v.z * v.z + v.w * v.w;
#pragma unroll
  for (int off = 1; off < 64; off <<= 1) {
    s += __shfl_xor(s, off);
    ss += __shfl_xor(ss, off);
  }
  __shared__ float rs[4], rss[4];
  if (lane == 0) { rs[wave] = s; rss[wave] = ss; }
  __syncthreads();
  const float S = rs[0] + rs[1] + rs[2] + rs[3];
  const float SS = rss[0] + rss[1] + rss[2] + rss[3];
  const float mean = S * (1.f / 1024.f);
  const float var = SS * (1.f / 1024.f) - mean * mean;
  const float inv = rsqrtf(var + 1e-5f);
  const float o0 = (v.x - mean) * inv, o1 = (v.y - mean) * inv;
  const float o2 = (v.z - mean) * inv, o3 = (v.w - mean) * inv;
  float4 fo; fo.x = o0; fo.y = o1; fo.z = o2; fo.w = o3;
  *(float4*)&xf[base] = fo;
  ushort4 ob;
  ob.x = f2bf(o0); ob.y = f2bf(o1); ob.z = f2bf(o2); ob.w = f2bf(o3);
  *(ushort4*)&xb[base] = ob;
  if (fout) *(float4*)&fout[base] = fo;
}

extern "C" void kernel_launch(void* const* d_in, const int* in_sizes, int n_in,
                              void* d_out, int out_size, void* d_ws, size_t ws_size,
                              hipStream_t stream) {
  const float* dec_inputs  = (const float*)d_in[0];
  const float* enc_outputs = (const float*)d_in[1];
  const float* self_Wq = (const float*)d_in[4];
  const float* self_Wk = (const float*)d_in[5];
  const float* self_Wv = (const float*)d_in[6];
  const float* self_Wo = (const float*)d_in[7];
  const float* cross_Wq = (const float*)d_in[8];
  const float* cross_Wk = (const float*)d_in[9];
  const float* cross_Wv = (const float*)d_in[10];
  const float* cross_Wo = (const float*)d_in[11];
  const float* ffn_W1 = (const float*)d_in[12];
  const float* ffn_W2 = (const float*)d_in[13];

  char* ws = (char*)d_ws;
  const size_t MB = 1024 * 1024;
  // bf16 weight staging (per layer, transposed to [N,K])
  u16* wq_t = (u16*)(ws + 0 * MB);   // [3072,1024] contiguous: wq,wk,wv
  u16* wk_t = (u16*)(ws + 2 * MB);
  u16* wv_t = (u16*)(ws + 4 * MB);
  u16* wo_t = (u16*)(ws + 6 * MB);
  u16* cq_t = (u16*)(ws + 8 * MB);
  u16* ck_t = (u16*)(ws + 10 * MB);  // [2048,1024] contiguous: ck,cv
  u16* cv_t = (u16*)(ws + 12 * MB);
  u16* co_t = (u16*)(ws + 14 * MB);
  u16* w1_t = (u16*)(ws + 16 * MB);  // [4096,1024]
  u16* w2_t = (u16*)(ws + 24 * MB);  // [1024,4096]
  u16* encb = (u16*)(ws + 32 * MB);  // [4096,1024] bf16
  u16* xb   = (u16*)(ws + 40 * MB);  // [4096,1024] bf16 copy of residual
  u16* qkv  = (u16*)(ws + 48 * MB);  // [4096,3072] self / cross q
  u16* kvb  = (u16*)(ws + 56 * MB);  // [4096,2048] cross K,V
  u16* ctx  = (u16*)(ws + 72 * MB);  // [4096,1024]
  u16* hbuf = (u16*)(ws + 48 * MB);  // [4096,4096] (overlays qkv+kvb+ctx in FFN)
  float* yb = (float*)(ws + 80 * MB);  // [4096,1024] f32 GEMM out
  u16* vtb  = (u16*)(ws + 80 * MB);    // [1024 ch][4096 tok] V^T (overlays yb; disjoint in time)
  float* xf = (float*)(ws + 96 * MB);  // [4096,1024] f32 residual stream
  // split-K second buffers (16 MB f32 each), placed over regions dead at their call site:
  float* ysA = (float*)(ws + 48 * MB); // over qkv/kvb: dead after flash (wo/co GEMMs)
  float* ysW = (float*)(ws + 0 * MB);  // over self/cross W_t: dead during FFN W2

  const int NTOK = 4 * TT * 1024;  // 4M elements

  k_init<<<4096, 256, 0, stream>>>(dec_inputs, xb, xf, NTOK);
  k_f32_to_bf16<<<4096, 256, 0, stream>>>(enc_outputs, encb, NTOK);

  for (int l = 0; l < 4; l++) {
    const size_t sqOff = (size_t)l * 1024 * 1024;
    const size_t ffOff = (size_t)l * 4096 * 1024;
    TPack sq;
    sq.src[0] = self_Wq + sqOff;  sq.dst[0] = wq_t;
    sq.src[1] = self_Wk + sqOff;  sq.dst[1] = wk_t;
    sq.src[2] = self_Wv + sqOff;  sq.dst[2] = wv_t;
    sq.src[3] = self_Wo + sqOff;  sq.dst[3] = wo_t;
    sq.src[4] = cross_Wq + sqOff; sq.dst[4] = cq_t;
    sq.src[5] = cross_Wk + sqOff; sq.dst[5] = ck_t;
    sq.src[6] = cross_Wv + sqOff; sq.dst[6] = cv_t;
    sq.src[7] = cross_Wo + sqOff; sq.dst[7] = co_t;
    k_transpose<<<dim3(32, 32, 8), 256, 0, stream>>>(sq, 1024, 1024);
    TPack p1 = sq; p1.src[0] = ffn_W1 + ffOff; p1.dst[0] = w1_t;
    k_transpose<<<dim3(128, 32, 1), 256, 0, stream>>>(p1, 1024, 4096);
    TPack p2 = sq; p2.src[0] = ffn_W2 + ffOff; p2.dst[0] = w2_t;
    k_transpose<<<dim3(32, 128, 1), 256, 0, stream>>>(p2, 4096, 1024);

    // ---- self attention ----
    k_gemm_tn<1, 0, 1><<<dim3(32, 24), 256, 0, stream>>>(xb, wq_t, qkv, nullptr, 4096, 3072, 1024);
    k_tbf<<<dim3(32, 128), 256, 0, stream>>>(qkv + 2048, 3072, vtb);
    k_flash<1><<<512, 512, 0, stream>>>(qkv, 3072, qkv + 1024, 3072, vtb, ctx);
    k_gemm_tn<0, 0, 2><<<dim3(32, 8, 2), 256, 0, stream>>>(ctx, wo_t, yb, ysA, 4096, 1024, 1024);
    k_ln<2><<<4096, 256, 0, stream>>>(yb, ysA, xf, xb, nullptr);

    // ---- cross attention ----
    k_gemm_tn<1, 0, 1><<<dim3(32, 8), 256, 0, stream>>>(xb, cq_t, qkv, nullptr, 4096, 1024, 1024);
    k_gemm_tn<1, 0, 1><<<dim3(32, 16), 256, 0, stream>>>(encb, ck_t, kvb, nullptr, 4096, 2048, 1024);
    k_tbf<<<dim3(32, 128), 256, 0, stream>>>(kvb + 1024, 2048, vtb);
    k_flash<0><<<512, 512, 0, stream>>>(qkv, 1024, kvb, 2048, vtb, ctx);
    k_gemm_tn<0, 0, 2><<<dim3(32, 8, 2), 256, 0, stream>>>(ctx, co_t, yb, ysA, 4096, 1024, 1024);
    k_ln<2><<<4096, 256, 0, stream>>>(yb, ysA, xf, xb, nullptr);

    // ---- FFN ----
    k_gemm_tn<1, 1, 1><<<dim3(32, 32), 256, 0, stream>>>(xb, w1_t, hbuf, nullptr, 4096, 4096, 1024);
    k_gemm_tn<0, 0, 2><<<dim3(32, 8, 2), 256, 0, stream>>>(hbuf, w2_t, yb, ysW, 4096, 1024, 4096);
    k_ln<2><<<4096, 256, 0, stream>>>(yb, ysW, xf, xb, (l == 3) ? (float*)d_out : nullptr);
  }
}

// Round 6
// 1774.982 us; speedup vs baseline: 1.1001x; 1.0175x over previous
//
#include <hip/hip_runtime.h>

typedef unsigned short u16;
typedef unsigned int u32;
typedef __bf16 bf16x8 __attribute__((ext_vector_type(8)));
typedef float f32x4 __attribute__((ext_vector_type(4)));

#define TT 1024

__device__ __forceinline__ u16 f2bf(float f) {
  u32 u = __float_as_uint(f);
  u32 r = (u + 0x7fffu + ((u >> 16) & 1u)) >> 16;
  return (u16)r;
}
__device__ __forceinline__ float bf2f(u16 b) {
  return __uint_as_float(((u32)b) << 16);
}

__device__ __forceinline__ void gl_lds16(const void* g, void* l) {
  __builtin_amdgcn_global_load_lds(
      (const __attribute__((address_space(1))) u32*)g,
      (__attribute__((address_space(3))) u32*)l, 16, 0, 0);
}

// ---------------- convert f32 -> bf16 ----------------
__global__ __launch_bounds__(256) void k_f32_to_bf16(const float* __restrict__ in,
                                                     u16* __restrict__ out, int n) {
  int i = (blockIdx.x * 256 + threadIdx.x) * 4;
  if (i >= n) return;
  float4 v = *(const float4*)(in + i);
  ushort4 o;
  o.x = f2bf(v.x); o.y = f2bf(v.y); o.z = f2bf(v.z); o.w = f2bf(v.w);
  *(ushort4*)(out + i) = o;
}

// ------- init residual: f32 copy + bf16 convert -------
__global__ __launch_bounds__(256) void k_init(const float* __restrict__ in,
                                              u16* __restrict__ bfo,
                                              float* __restrict__ fo, int n) {
  int i = (blockIdx.x * 256 + threadIdx.x) * 4;
  if (i >= n) return;
  float4 v = *(const float4*)(in + i);
  ushort4 o;
  o.x = f2bf(v.x); o.y = f2bf(v.y); o.z = f2bf(v.z); o.w = f2bf(v.w);
  *(ushort4*)(bfo + i) = o;
  *(float4*)(fo + i) = v;
}

// ------- transpose+convert: src f32 [R][C] -> dst bf16 [C][R] -------
struct TPack {
  const float* src[8];
  u16* dst[8];
};
__global__ __launch_bounds__(256) void k_transpose(TPack p, int R, int C) {
  __shared__ float tile[32][33];
  const int tx = threadIdx.x & 31;
  const int ty = threadIdx.x >> 5;
  const float* __restrict__ src = p.src[blockIdx.z];
  u16* __restrict__ dst = p.dst[blockIdx.z];
  const int c0 = blockIdx.x * 32;
  const int r0 = blockIdx.y * 32;
#pragma unroll
  for (int i = 0; i < 4; i++)
    tile[ty + i * 8][tx] = src[(size_t)(r0 + ty + i * 8) * C + c0 + tx];
  __syncthreads();
#pragma unroll
  for (int i = 0; i < 4; i++)
    dst[(size_t)(c0 + ty + i * 8) * R + r0 + tx] = f2bf(tile[tx][ty + i * 8]);
}

// ------- bf16 transpose: src [4096 rows][1024 cols within stride ld] -> dst [1024][4096] -------
__global__ __launch_bounds__(256) void k_tbf(const u16* __restrict__ src, int ld,
                                             u16* __restrict__ dst) {
  __shared__ u16 tile[32][33];
  const int r0 = blockIdx.y * 32;  // token tile
  const int c0 = blockIdx.x * 32;  // channel tile
  const int tr = threadIdx.x >> 3;        // 0..31
  const int tc = (threadIdx.x & 7) * 4;   // 0,4,..,28
  ushort4 v = *(const ushort4*)&src[(size_t)(r0 + tr) * ld + c0 + tc];
  tile[tr][tc] = v.x; tile[tr][tc + 1] = v.y; tile[tr][tc + 2] = v.z; tile[tr][tc + 3] = v.w;
  __syncthreads();
  ushort4 o;
  o.x = tile[tc][tr]; o.y = tile[tc + 1][tr]; o.z = tile[tc + 2][tr]; o.w = tile[tc + 3][tr];
  *(ushort4*)&dst[(size_t)(c0 + tr) * 4096 + r0 + tc] = o;
}

// ---------------- GEMM: C[M,N] = A[M,K] @ Bt[N,K]^T (bf16 in, f32 acc) ----------------
// 3-deep LDS pipeline, raw s_barrier + counted vmcnt(4): the prefetch issued at
// iter i lands during iters i..i+1 (~2 K-steps of MFMA cover) instead of being
// drained by __syncthreads()' vmcnt(0) after one.  Race-free: buffer (i+2)%3 is
// overwritten at iter i, strictly after the post-MFMA barrier of iter i-1 which
// read it.  LDS chunk-swizzle: source chunk = (lane&3)^((srow>>1)&3), read chunk
// = quad^((lc>>1)&3) -> conflict-free ds_read_b128.
// SPLITK>1: blockIdx.z selects a K-slice; z==0 writes Cout, z==1 writes Cout2 (f32 only).
template <int OUT_BF16, int RELU, int SPLITK>
__global__ __launch_bounds__(256) void k_gemm_tn(const u16* __restrict__ A,
                                                 const u16* __restrict__ Bt,
                                                 void* __restrict__ Cout,
                                                 void* __restrict__ Cout2,
                                                 int M, int N, int K) {
  __shared__ __attribute__((aligned(16))) u16 sA[3][128 * 32];
  __shared__ __attribute__((aligned(16))) u16 sB[3][128 * 32];
  const int tid = threadIdx.x;
  const int wave = tid >> 6;
  const int lane = tid & 63;
  const int quad = lane >> 4;
  const int lc = lane & 15;
  const int m0 = blockIdx.x * 128;
  const int n0 = blockIdx.y * 128;
  const int wr = (wave >> 1) * 64;
  const int wc = (wave & 1) * 64;

  const int Ks = K / SPLITK;
  const size_t kOff = (size_t)blockIdx.z * Ks;

  const int c0 = wave * 2, c1 = wave * 2 + 1;
  const int srow = lane >> 2;
  // inverse-swizzled source chunk (pairs with swizzled read below)
  const int scol = ((lane & 3) ^ ((srow >> 1) & 3)) * 8;

  const u16* a0 = A + (size_t)(m0 + c0 * 16 + srow) * K + kOff + scol;
  const u16* a1 = A + (size_t)(m0 + c1 * 16 + srow) * K + kOff + scol;
  const u16* b0 = Bt + (size_t)(n0 + c0 * 16 + srow) * K + kOff + scol;
  const u16* b1 = Bt + (size_t)(n0 + c1 * 16 + srow) * K + kOff + scol;

  f32x4 acc[4][4];
  const f32x4 z4 = {0.f, 0.f, 0.f, 0.f};
#pragma unroll
  for (int i = 0; i < 4; i++)
#pragma unroll
    for (int j = 0; j < 4; j++) acc[i][j] = z4;

  const int qs = quad ^ ((lc >> 1) & 3);  // swizzled read chunk

  auto stage = [&](int buf) {
    gl_lds16(a0, &sA[buf][c0 * 512]);
    gl_lds16(a1, &sA[buf][c1 * 512]);
    gl_lds16(b0, &sB[buf][c0 * 512]);
    gl_lds16(b1, &sB[buf][c1 * 512]);
    a0 += 32; a1 += 32; b0 += 32; b1 += 32;
  };

  stage(0);
  stage(1);
  int cur = 0, nxt = 2;
  const int nsteps = Ks / 32;  // >= 16 for all call sites
  for (int it = 0; it < nsteps; ++it) {
    // my stage from 2 iters ago has retired; only the newest 4 loads may remain
    asm volatile("s_waitcnt vmcnt(4)" ::: "memory");
    __builtin_amdgcn_s_barrier();  // all waves' quarters of buf[cur] are resident
    if (it + 2 < nsteps) stage(nxt);  // overwrite oldest buffer (read finished last iter)
    bf16x8 af[4], bfr[4];
#pragma unroll
    for (int i = 0; i < 4; i++)
      af[i] = *(const bf16x8*)&sA[cur][(wr + i * 16 + lc) * 32 + qs * 8];
#pragma unroll
    for (int j = 0; j < 4; j++)
      bfr[j] = *(const bf16x8*)&sB[cur][(wc + j * 16 + lc) * 32 + qs * 8];
#pragma unroll
    for (int i = 0; i < 4; i++)
#pragma unroll
      for (int j = 0; j < 4; j++)
        acc[i][j] = __builtin_amdgcn_mfma_f32_16x16x32_bf16(af[i], bfr[j], acc[i][j], 0, 0, 0);
    __builtin_amdgcn_s_barrier();  // everyone's ds_reads of buf[cur] are done
    cur = (cur == 2) ? 0 : cur + 1;
    nxt = (nxt == 2) ? 0 : nxt + 1;
  }

  void* Cw = (SPLITK > 1 && blockIdx.z == 1) ? Cout2 : Cout;
#pragma unroll
  for (int i = 0; i < 4; i++) {
    const int row = m0 + wr + i * 16 + quad * 4;
#pragma unroll
    for (int j = 0; j < 4; j++) {
      const int col = n0 + wc + j * 16 + lc;
#pragma unroll
      for (int r = 0; r < 4; r++) {
        float v = acc[i][j][r];
        if (RELU) v = fmaxf(v, 0.f);
        if (OUT_BF16)
          ((u16*)Cw)[(size_t)(row + r) * N + col] = f2bf(v);
        else
          ((float*)Cw)[(size_t)(row + r) * N + col] = v;
      }
    }
  }
}

// ---------------- flash attention (T=S=1024, H=16, D=64) ----------------
// QBLK=128 (8 waves), 1D grid 512 with XCD-aware remap: each XCD owns 8 heads
// (2 MB K/V -> fits per-XCD L2). K: [token][ch] stride ldk; Vt: [1024 ch][4096 tok].
// KVBLK=64, double-buffered LDS via global_load_lds with XOR-swizzled source,
// swizzled ds_read_b128 fragment reads; 1 barrier per tile; deferred l-sum.
// NOTE: min-waves hint = 4 (NOT 6): 6 capped VGPR at 40 -> accumulator spills,
// WRITE_SIZE 8MB->85MB scratch traffic (round-4 regression). LDS already limits
// to 3 blocks/CU; VGPR cap 128 keeps all state resident.
template <int CAUSAL>
__global__ __launch_bounds__(512, 4) void k_flash(const u16* __restrict__ Q, int ldq,
                                                  const u16* __restrict__ K, int ldk,
                                                  const u16* __restrict__ Vt,
                                                  u16* __restrict__ O) {
  __shared__ __attribute__((aligned(16))) u16 sK[2][64 * 64];  // [key][dk], dk-blocks swizzled
  __shared__ __attribute__((aligned(16))) u16 sV[2][64 * 64];  // [dv][key], key-blocks swizzled
  __shared__ __attribute__((aligned(16))) u16 sP[8][16 * 64];  // per-wave, key-blocks swizzled
  const int tid = threadIdx.x;
  const int wave = tid >> 6;
  const int lane = tid & 63;
  const int quad = lane >> 4;
  const int lc = lane & 15;
  // XCD-aware remap: 512 blocks, xcd = id&7 owns heads y in [xcd*8, xcd*8+8)
  const int id = blockIdx.x;
  const int xcd = id & 7;
  const int s_ = id >> 3;          // 0..63
  const int y = xcd * 8 + (s_ >> 3);  // 0..63 (b,h pair)
  const int qb = s_ & 7;           // 0..7
  const int b = y >> 4;            // batch
  const int h = y & 15;            // head
  const size_t rowB = (size_t)b * TT;
  const int qrow = qb * 128 + wave * 16;
  const int hc = h * 64;

  const bf16x8 qf0 = *(const bf16x8*)&Q[(rowB + qrow + lc) * ldq + hc + quad * 8];
  const bf16x8 qf1 = *(const bf16x8*)&Q[(rowB + qrow + lc) * ldq + hc + 32 + quad * 8];

  f32x4 o[4];
  float m_r[4], l_r[4];
  const f32x4 z4 = {0.f, 0.f, 0.f, 0.f};
#pragma unroll
  for (int d = 0; d < 4; d++) o[d] = z4;
#pragma unroll
  for (int r = 0; r < 4; r++) { m_r[r] = -1e30f; l_r[r] = 0.f; }

  const float cvt = 1.4426950408889634f / 8.0f;  // log2(e)/sqrt(DK)
  u16* myP = sP[wave];
  const int l7 = lc & 7;
  const int swr = (lc >> 2) | ((lc & 1) << 2);  // P-read swizzle sw(row=lc)

  const int nkt = CAUSAL ? (2 * qb + 2) : 16;

  // staging: 512 threads cover 512 chunks of 16B per array (1 gl_lds each)
  const int prow = tid >> 3;                 // 0..63
  const int pcb = (tid & 7) ^ (prow & 7);    // inverse-swizzled source block
  const int p0 = wave * 64;                  // wave-uniform LDS base chunk

  auto stage = [&](int cur, int s0) {
    gl_lds16(K + (rowB + s0 + prow) * (size_t)ldk + hc + pcb * 8, &sK[cur][p0 * 8]);
    gl_lds16(Vt + (size_t)(hc + prow) * 4096 + rowB + s0 + pcb * 8, &sV[cur][p0 * 8]);
  };

  stage(0, 0);
  int cur = 0;
  for (int kt = 0; kt < nkt; kt++) {
    const int s0 = kt * 64;
    __syncthreads();  // drains vmcnt(0): buf[cur] ready; buf[cur^1] free for prefetch
    if (kt + 1 < nkt) stage(cur ^ 1, s0 + 64);

    // S = Q @ K^T : 4 sub-tiles of 16 keys
    f32x4 s[4];
#pragma unroll
    for (int st = 0; st < 4; st++) {
      const int key = st * 16 + lc;
      const bf16x8 kf0 = *(const bf16x8*)&sK[cur][key * 64 + ((quad ^ l7) * 8)];
      const bf16x8 kf1 = *(const bf16x8*)&sK[cur][key * 64 + (((4 + quad) ^ l7) * 8)];
      f32x4 z = z4;
      z = __builtin_amdgcn_mfma_f32_16x16x32_bf16(qf0, kf0, z, 0, 0, 0);
      z = __builtin_amdgcn_mfma_f32_16x16x32_bf16(qf1, kf1, z, 0, 0, 0);
      s[st] = z;
    }

    // online softmax (log2 domain); l kept as per-lane partial (reduced at end)
#pragma unroll
    for (int r = 0; r < 4; r++) {
      float sv0 = s[0][r] * cvt, sv1 = s[1][r] * cvt;
      float sv2 = s[2][r] * cvt, sv3 = s[3][r] * cvt;
      if (CAUSAL) {
        const int qg = qrow + quad * 4 + r;
        if (s0 + lc > qg) sv0 = -1e30f;
        if (s0 + 16 + lc > qg) sv1 = -1e30f;
        if (s0 + 32 + lc > qg) sv2 = -1e30f;
        if (s0 + 48 + lc > qg) sv3 = -1e30f;
      }
      float pm = fmaxf(fmaxf(sv0, sv1), fmaxf(sv2, sv3));
      pm = fmaxf(pm, __shfl_xor(pm, 1));
      pm = fmaxf(pm, __shfl_xor(pm, 2));
      pm = fmaxf(pm, __shfl_xor(pm, 4));
      pm = fmaxf(pm, __shfl_xor(pm, 8));
      const float mn = fmaxf(m_r[r], pm);
      const float al = exp2f(m_r[r] - mn);
      m_r[r] = mn;
      const float p0_ = exp2f(sv0 - mn);
      const float p1_ = exp2f(sv1 - mn);
      const float p2_ = exp2f(sv2 - mn);
      const float p3_ = exp2f(sv3 - mn);
      l_r[r] = l_r[r] * al + (p0_ + p1_ + p2_ + p3_);
      const int row = quad * 4 + r;
      const int sw = quad | ((r & 1) << 2);  // P-write swizzle sw(row)
      u16* pr = myP + row * 64 + l7;
      pr[(((lc >> 3) | 0) ^ sw) * 8] = f2bf(p0_);
      pr[(((lc >> 3) | 2) ^ sw) * 8] = f2bf(p1_);
      pr[(((lc >> 3) | 4) ^ sw) * 8] = f2bf(p2_);
      pr[(((lc >> 3) | 6) ^ sw) * 8] = f2bf(p3_);
#pragma unroll
      for (int d = 0; d < 4; d++) o[d][r] *= al;
    }

    // O += P @ V : two 32-key chunks (sP is per-wave private: no barrier needed)
#pragma unroll
    for (int c = 0; c < 2; c++) {
      const bf16x8 pf = *(const bf16x8*)&myP[lc * 64 + (((c * 4 + quad) ^ swr) * 8)];
#pragma unroll
      for (int d = 0; d < 4; d++) {
        const int dv = d * 16 + lc;
        const bf16x8 vf = *(const bf16x8*)&sV[cur][dv * 64 + (((c * 4 + quad) ^ l7) * 8)];
        o[d] = __builtin_amdgcn_mfma_f32_16x16x32_bf16(pf, vf, o[d], 0, 0, 0);
      }
    }
    cur ^= 1;
  }

#pragma unroll
  for (int r = 0; r < 4; r++) {
    float l = l_r[r];
    l += __shfl_xor(l, 1);
    l += __shfl_xor(l, 2);
    l += __shfl_xor(l, 4);
    l += __shfl_xor(l, 8);
    const float inv = 1.0f / l;
    const size_t orow = (rowB + qrow + quad * 4 + r) * 1024 + hc;
#pragma unroll
    for (int d = 0; d < 4; d++) O[orow + d * 16 + lc] = f2bf(o[d][r] * inv);
  }
}

// --------- residual + layernorm: xf = LN(y0 [+ y1] + xf) [f32]; xb = bf16(xf) ---------
template <int NSUM>
__global__ __launch_bounds__(256) void k_ln(const float* __restrict__ y0,
                                            const float* __restrict__ y1,
                                            float* __restrict__ xf,
                                            u16* __restrict__ xb,
                                            float* __restrict__ fout) {
  const int row = blockIdx.x;
  const int tid = threadIdx.x;
  const int lane = tid & 63, wave = tid >> 6;
  const size_t base = (size_t)row * 1024 + tid * 4;
  float4 v = *(const float4*)&y0[base];
  float4 xv = *(const float4*)&xf[base];
  if (NSUM == 2) {
    float4 w = *(const float4*)&y1[base];
    v.x += w.x; v.y += w.y; v.z += w.z; v.w += w.w;
  }
  v.x += xv.x; v.y += xv.y; v.z += xv.z; v.w += xv.w;
  float s = v.x + v.y + v.z + v.w;
  float ss = v.x * v.x + v.y * v.y + v.z * v.z + v.w * v.w;
#pragma unroll
  for (int off = 1; off < 64; off <<= 1) {
    s += __shfl_xor(s, off);
    ss += __shfl_xor(ss, off);
  }
  __shared__ float rs[4], rss[4];
  if (lane == 0) { rs[wave] = s; rss[wave] = ss; }
  __syncthreads();
  const float S = rs[0] + rs[1] + rs[2] + rs[3];
  const float SS = rss[0] + rss[1] + rss[2] + rss[3];
  const float mean = S * (1.f / 1024.f);
  const float var = SS * (1.f / 1024.f) - mean * mean;
  const float inv = rsqrtf(var + 1e-5f);
  const float o0 = (v.x - mean) * inv, o1 = (v.y - mean) * inv;
  const float o2 = (v.z - mean) * inv, o3 = (v.w - mean) * inv;
  float4 fo; fo.x = o0; fo.y = o1; fo.z = o2; fo.w = o3;
  *(float4*)&xf[base] = fo;
  ushort4 ob;
  ob.x = f2bf(o0); ob.y = f2bf(o1); ob.z = f2bf(o2); ob.w = f2bf(o3);
  *(ushort4*)&xb[base] = ob;
  if (fout) *(float4*)&fout[base] = fo;
}

extern "C" void kernel_launch(void* const* d_in, const int* in_sizes, int n_in,
                              void* d_out, int out_size, void* d_ws, size_t ws_size,
                              hipStream_t stream) {
  const float* dec_inputs  = (const float*)d_in[0];
  const float* enc_outputs = (const float*)d_in[1];
  const float* self_Wq = (const float*)d_in[4];
  const float* self_Wk = (const float*)d_in[5];
  const float* self_Wv = (const float*)d_in[6];
  const float* self_Wo = (const float*)d_in[7];
  const float* cross_Wq = (const float*)d_in[8];
  const float* cross_Wk = (const float*)d_in[9];
  const float* cross_Wv = (const float*)d_in[10];
  const float* cross_Wo = (const float*)d_in[11];
  const float* ffn_W1 = (const float*)d_in[12];
  const float* ffn_W2 = (const float*)d_in[13];

  char* ws = (char*)d_ws;
  const size_t MB = 1024 * 1024;
  // bf16 weight staging (per layer, transposed to [N,K])
  u16* wq_t = (u16*)(ws + 0 * MB);   // [3072,1024] contiguous: wq,wk,wv
  u16* wk_t = (u16*)(ws + 2 * MB);
  u16* wv_t = (u16*)(ws + 4 * MB);
  u16* wo_t = (u16*)(ws + 6 * MB);
  u16* cq_t = (u16*)(ws + 8 * MB);
  u16* ck_t = (u16*)(ws + 10 * MB);  // [2048,1024] contiguous: ck,cv
  u16* cv_t = (u16*)(ws + 12 * MB);
  u16* co_t = (u16*)(ws + 14 * MB);
  u16* w1_t = (u16*)(ws + 16 * MB);  // [4096,1024]
  u16* w2_t = (u16*)(ws + 24 * MB);  // [1024,4096]
  u16* encb = (u16*)(ws + 32 * MB);  // [4096,1024] bf16
  u16* xb   = (u16*)(ws + 40 * MB);  // [4096,1024] bf16 copy of residual
  u16* qkv  = (u16*)(ws + 48 * MB);  // [4096,3072] self / cross q
  u16* kvb  = (u16*)(ws + 56 * MB);  // [4096,2048] cross K,V
  u16* ctx  = (u16*)(ws + 72 * MB);  // [4096,1024]
  u16* hbuf = (u16*)(ws + 48 * MB);  // [4096,4096] (overlays qkv+kvb+ctx in FFN)
  float* yb = (float*)(ws + 80 * MB);  // [4096,1024] f32 GEMM out
  u16* vtb  = (u16*)(ws + 80 * MB);    // [1024 ch][4096 tok] V^T (overlays yb; disjoint in time)
  float* xf = (float*)(ws + 96 * MB);  // [4096,1024] f32 residual stream
  // split-K second buffers (16 MB f32 each), placed over regions dead at their call site:
  float* ysA = (float*)(ws + 48 * MB); // over qkv/kvb: dead after flash (wo/co GEMMs)
  float* ysW = (float*)(ws + 0 * MB);  // over self/cross W_t: dead during FFN W2

  const int NTOK = 4 * TT * 1024;  // 4M elements

  k_init<<<4096, 256, 0, stream>>>(dec_inputs, xb, xf, NTOK);
  k_f32_to_bf16<<<4096, 256, 0, stream>>>(enc_outputs, encb, NTOK);

  for (int l = 0; l < 4; l++) {
    const size_t sqOff = (size_t)l * 1024 * 1024;
    const size_t ffOff = (size_t)l * 4096 * 1024;
    TPack sq;
    sq.src[0] = self_Wq + sqOff;  sq.dst[0] = wq_t;
    sq.src[1] = self_Wk + sqOff;  sq.dst[1] = wk_t;
    sq.src[2] = self_Wv + sqOff;  sq.dst[2] = wv_t;
    sq.src[3] = self_Wo + sqOff;  sq.dst[3] = wo_t;
    sq.src[4] = cross_Wq + sqOff; sq.dst[4] = cq_t;
    sq.src[5] = cross_Wk + sqOff; sq.dst[5] = ck_t;
    sq.src[6] = cross_Wv + sqOff; sq.dst[6] = cv_t;
    sq.src[7] = cross_Wo + sqOff; sq.dst[7] = co_t;
    k_transpose<<<dim3(32, 32, 8), 256, 0, stream>>>(sq, 1024, 1024);
    TPack p1 = sq; p1.src[0] = ffn_W1 + ffOff; p1.dst[0] = w1_t;
    k_transpose<<<dim3(128, 32, 1), 256, 0, stream>>>(p1, 1024, 4096);
    TPack p2 = sq; p2.src[0] = ffn_W2 + ffOff; p2.dst[0] = w2_t;
    k_transpose<<<dim3(32, 128, 1), 256, 0, stream>>>(p2, 4096, 1024);

    // ---- self attention ----
    k_gemm_tn<1, 0, 1><<<dim3(32, 24), 256, 0, stream>>>(xb, wq_t, qkv, nullptr, 4096, 3072, 1024);
    k_tbf<<<dim3(32, 128), 256, 0, stream>>>(qkv + 2048, 3072, vtb);
    k_flash<1><<<512, 512, 0, stream>>>(qkv, 3072, qkv + 1024, 3072, vtb, ctx);
    k_gemm_tn<0, 0, 2><<<dim3(32, 8, 2), 256, 0, stream>>>(ctx, wo_t, yb, ysA, 4096, 1024, 1024);
    k_ln<2><<<4096, 256, 0, stream>>>(yb, ysA, xf, xb, nullptr);

    // ---- cross attention ----
    k_gemm_tn<1, 0, 1><<<dim3(32, 8), 256, 0, stream>>>(xb, cq_t, qkv, nullptr, 4096, 1024, 1024);
    k_gemm_tn<1, 0, 1><<<dim3(32, 16), 256, 0, stream>>>(encb, ck_t, kvb, nullptr, 4096, 2048, 1024);
    k_tbf<<<dim3(32, 128), 256, 0, stream>>>(kvb + 1024, 2048, vtb);
    k_flash<0><<<512, 512, 0, stream>>>(qkv, 1024, kvb, 2048, vtb, ctx);
    k_gemm_tn<0, 0, 2><<<dim3(32, 8, 2), 256, 0, stream>>>(ctx, co_t, yb, ysA, 4096, 1024, 1024);
    k_ln<2><<<4096, 256, 0, stream>>>(yb, ysA, xf, xb, nullptr);

    // ---- FFN ----
    k_gemm_tn<1, 1, 1><<<dim3(32, 32), 256, 0, stream>>>(xb, w1_t, hbuf, nullptr, 4096, 4096, 1024);
    k_gemm_tn<0, 0, 2><<<dim3(32, 8, 2), 256, 0, stream>>>(hbuf, w2_t, yb, ysW, 4096, 1024, 4096);
    k_ln<2><<<4096, 256, 0, stream>>>(yb, ysW, xf, xb, (l == 3) ? (float*)d_out : nullptr);
  }
}